// Round 9
// baseline (35.339 us; speedup 1.0000x reference)
//
#include <hip/hip_runtime.h>

// Spectral conv, 2 dispatches:
//   K1 (k_cft):    X[bc][m] = sum_l T[l][m] * (sum_k xq[bc][l,k] * F[k][m])
//                  + zeroes the 8 per-b barrier counters for K2.
//   K2 (k_mixicft): phase C: Y = mix(X,W); Z[b][o][s] (system-scope stores)
//                   per-b barrier (64 blocks, relaxed agent atomics, no fences)
//                   phase D: out = sum_s Re(Z * wf_s e^{2pi i fq_s t_j})
// Z goes through the coherence point (system-scope stores) so no L2
// writeback/invalidate is needed; counters are the only cross-block sync.

#define NN 4096
#define C1_19 0.9863613034027223   // cos(pi/19)
#define NS3 33
#define NSP 40

// ws float offsets
#define OFF_XRE 0                  // X real [512*64]
#define OFF_XIM 32768
#define OFF_Z   65536              // Z [2][512][NSP]
#define OFF_CNT 106496             // 8 uint counters, stride 16

__device__ __forceinline__ float sin_rev(float r) { return __builtin_amdgcn_sinf(r); }
__device__ __forceinline__ float cos_rev(float r) { return __builtin_amdgcn_cosf(r); }

// nd[k] = cos(pi k/19); cwd[k] = CC weight (endpoints halved). No libm.
// Contains one __syncthreads; caller must sync again before using cwd.
__device__ __forceinline__ void build_tables(double* nd, double* cwd, int t) {
    if (t == 0) {
        nd[0] = 1.0; nd[1] = C1_19;
        for (int k = 2; k < 20; ++k) nd[k] = 2.0 * C1_19 * nd[k - 1] - nd[k - 2];
    }
    __syncthreads();
    if (t < 20) {
        double v = 1.0;
        for (int j = 1; j <= 9; ++j) {
            int q = (2 * j * t) % 38; if (q > 19) q = 38 - q;   // cos(2pi j t/19)
            v -= 2.0 / (4.0 * j * j - 1.0) * nd[q];
        }
        double w = 2.0 * v / 19.0;
        if (t == 0 || t == 19) w *= 0.5;
        cwd[t] = w;
    }
}

// ---------- K1: full CFT, one bc row per block; zero K2 counters ----------
__global__ __launch_bounds__(256) void k_cft(const float* __restrict__ x,
                                             float* __restrict__ ws) {
    __shared__ double nd[20], cwd[20];
    __shared__ __align__(16) float xs[NN];
    __shared__ __align__(16) float xq[2000];
    __shared__ __align__(16) float Fri[20][64][2];
    __shared__ float red[4][64][2];
    const int t = threadIdx.x;
    const int bc = blockIdx.x;
    if (bc == 0 && t < 8)
        __hip_atomic_store((unsigned*)ws + OFF_CNT + t * 16, 0u,
                           __ATOMIC_RELAXED, __HIP_MEMORY_SCOPE_SYSTEM);
    build_tables(nd, cwd, t);
#pragma unroll
    for (int it = 0; it < 4; ++it) {
        int c4 = it * 256 + t;
        *(float4*)&xs[c4 * 4] = *(const float4*)&x[(size_t)bc * NN + c4 * 4];
    }
    __syncthreads();
    // F[k][m] = 0.005*w_k * exp(-2pi i * 0.005*m*node_k)
    for (int idx = t; idx < 1280; idx += 256) {
        int k = idx >> 6, m = idx & 63;
        double r = -0.005 * nd[k] * (double)m;
        r -= floor(r);
        float fr = (float)r;
        float w = (float)(0.005 * cwd[k]);
        Fri[k][m][0] = w * cos_rev(fr);
        Fri[k][m][1] = w * sin_rev(fr);
    }
    // xq: interp x onto the 2000 Chebyshev quadrature nodes
#pragma unroll
    for (int it = 0; it < 8; ++it) {
        int node = it * 256 + t;
        if (node < 2000) {
            int l = node / 20, k = node - l * 20;
            double tq = 0.005 * ((double)(2 * l + 1) + nd[k]);
            double sf = tq * 4095.0;
            int i = (int)sf; if (i > 4094) i = 4094;
            double a = sf - (double)i;
            if (a < 0.0) a = 0.0; if (a > 1.0) a = 1.0;
            float af = (float)a;
            xq[node] = (1.f - af) * xs[i] + af * xs[i + 1];
        }
    }
    __syncthreads();
    const int m = t & 63, grp = t >> 6;
    float Fre[20], Fim[20];
#pragma unroll
    for (int k = 0; k < 20; ++k) {
        Fre[k] = Fri[k][m][0];
        Fim[k] = Fri[k][m][1];
    }
    // main loop: exact integer twiddle phase u/200 (sign folded: sin -> -sin)
    float ar = 0.f, ai = 0.f;
    for (int l = grp * 25; l < grp * 25 + 25; ++l) {
        const float4* q4 = (const float4*)&xq[l * 20];   // wave-uniform addr
        float ur = 0.f, ui = 0.f;
#pragma unroll
        for (int c = 0; c < 5; ++c) {
            float4 q = q4[c];
            ur += q.x * Fre[c * 4]     + q.y * Fre[c * 4 + 1]
                + q.z * Fre[c * 4 + 2] + q.w * Fre[c * 4 + 3];
            ui += q.x * Fim[c * 4]     + q.y * Fim[c * 4 + 1]
                + q.z * Fim[c * 4 + 2] + q.w * Fim[c * 4 + 3];
        }
        int u = (m * (2 * l + 1)) % 200;                 // phase = -u/200 rev
        float fr = (float)u * 0.005f;
        float tr = cos_rev(fr), ti = -sin_rev(fr);
        ar += tr * ur - ti * ui;
        ai += tr * ui + ti * ur;
    }
    red[grp][m][0] = ar;
    red[grp][m][1] = ai;
    __syncthreads();
    if (t < 64) {
        float sr = (red[0][t][0] + red[1][t][0]) + (red[2][t][0] + red[3][t][0]);
        float si = (red[0][t][1] + red[1][t][1]) + (red[2][t][1] + red[3][t][1]);
        ws[OFF_XRE + (size_t)bc * 64 + t] = sr;
        ws[OFF_XIM + (size_t)bc * 64 + t] = si;
    }
}

// ---------- K2: mix+Z, per-b barrier, ICFT. grid 512 = (b<<6 | u) ----------
struct PhC { float part[4][2][64]; float yt[2][64]; };
struct PhD { float zt[2][64][41]; float e2[2][NSP][64]; };
union SU2 { PhC c; PhD d; };

__global__ __launch_bounds__(256) void k_mixicft(const float* __restrict__ wr,
                                                 const float* __restrict__ wi,
                                                 float* __restrict__ ws,
                                                 float* __restrict__ out) {
    __shared__ SU2 su;
    __shared__ double nd[20], cwd[20];
    __shared__ float sw0[NS3], sw1[NS3];
    __shared__ int   si0[NS3], si1[NS3];
    __shared__ double sfq[NS3];
    __shared__ float  swf[NS3];
    const int t = threadIdx.x;
    const int b = blockIdx.x >> 6, u = blockIdx.x & 63;
    build_tables(nd, cwd, t);
    __syncthreads();
    if (t < NS3) {
        int l = (t < 2) ? 49 : (t < 22 ? 50 : 51);
        int k = (t < 2) ? t : (t < 22 ? t - 2 : t - 13);
        double fq = -2048.0 + ((double)l + 0.5) * 40.95 + 20.475 * nd[k];
        sfq[t] = fq;
        swf[t] = (float)(20.475 * cwd[k]);
        int m0 = (int)floor(fq);
        float fr = (float)(fq - (double)m0);
        sw0[t] = (m0 >= 0 && m0 <= 63) ? (1.f - fr) : 0.f;
        sw1[t] = (m0 + 1 >= 0 && m0 + 1 <= 63) ? fr : 0.f;
        si0[t] = min(max(m0, 0), 63);
        si1[t] = min(max(m0 + 1, 0), 63);
    }
    // ---- phase C: Y[b][o=u][m], then Z (system-scope stores) ----
    {
        const int o = u;
        const int m = t & 63, grp = t >> 6;
        float yr = 0.f, yi = 0.f;
#pragma unroll 4
        for (int i = grp * 16; i < grp * 16 + 16; ++i) {
            float xr = ws[OFF_XRE + (size_t)(b * 64 + i) * 64 + m];
            float xi = ws[OFF_XIM + (size_t)(b * 64 + i) * 64 + m];
            float a = wr[((size_t)i * 64 + o) * 64 + m];
            float c = wi[((size_t)i * 64 + o) * 64 + m];
            yr += xr * a - xi * c;
            yi += xr * c + xi * a;
        }
        su.c.part[grp][0][m] = yr;
        su.c.part[grp][1][m] = yi;
        __syncthreads();
        if (t < 128) {
            int pr = t >> 6, mm = t & 63;
            su.c.yt[pr][mm] = ((su.c.part[0][pr][mm] + su.c.part[1][pr][mm]) +
                               (su.c.part[2][pr][mm] + su.c.part[3][pr][mm]));
        }
        __syncthreads();
        if (t < 2 * NS3) {
            int p = t >= NS3, s = t - p * NS3;
            float z = sw0[s] * su.c.yt[p][si0[s]] + sw1[s] * su.c.yt[p][si1[s]];
            __hip_atomic_store(&ws[OFF_Z + (size_t)p * 512 * NSP +
                                   ((size_t)b * 64 + o) * NSP + s],
                               z, __ATOMIC_RELAXED, __HIP_MEMORY_SCOPE_SYSTEM);
        } else if (t < 2 * NS3 + 14) {
            int q = t - 2 * NS3;
            int p = q / 7, s = NS3 + q % 7;
            __hip_atomic_store(&ws[OFF_Z + (size_t)p * 512 * NSP +
                                   ((size_t)b * 64 + o) * NSP + s],
                               0.f, __ATOMIC_RELAXED, __HIP_MEMORY_SCOPE_SYSTEM);
        }
    }
    // ---- per-b barrier: 64 producers of this b -> consumers (pc=b) ----
    __syncthreads();                       // drains vmcnt(0) before s_barrier
    if (t == 0) {
        unsigned* cnt = (unsigned*)ws + OFF_CNT + b * 16;
        __hip_atomic_fetch_add(cnt, 1u, __ATOMIC_RELAXED, __HIP_MEMORY_SCOPE_AGENT);
        while (__hip_atomic_load(cnt, __ATOMIC_RELAXED, __HIP_MEMORY_SCOPE_AGENT) < 64u)
            __builtin_amdgcn_s_sleep(4);
    }
    __syncthreads();
    // ---- phase D: ICFT for (pc=b, jt=u) ----
    {
        const int jt = u, pc = b;
        for (int idx = t; idx < 2 * 64 * NSP; idx += 256) {
            int part = idx / (64 * NSP), rem = idx % (64 * NSP);
            int row = rem / NSP, s = rem % NSP;
            su.d.zt[part][row][s] =
                ws[OFF_Z + (size_t)part * 512 * NSP + ((size_t)pc * 64 + row) * NSP + s];
        }
        __syncthreads();
        const double inv4095 = 1.0 / 4095.0;
        for (int idx = t; idx < NSP * 64; idx += 256) {
            int s = idx >> 6, jl = idx & 63;
            float cr = 0.f, ci = 0.f;
            if (s < NS3) {
                double ph = sfq[s] * ((double)(jt * 64 + jl) * inv4095);
                ph -= floor(ph);
                float fr = (float)ph;
                cr = swf[s] * cos_rev(fr);
                ci = swf[s] * sin_rev(fr);
            }
            su.d.e2[0][s][jl] = cr;
            su.d.e2[1][s][jl] = ci;
        }
        __syncthreads();
        const int jg = t & 15, pg = t >> 4;
        float acc[4][4] = {{0.f}};
        for (int s0 = 0; s0 < NSP; s0 += 8) {
            float zr[4][8], zi[4][8];
#pragma unroll
            for (int p = 0; p < 4; ++p)
#pragma unroll
                for (int v = 0; v < 8; ++v) {
                    zr[p][v] = su.d.zt[0][pg * 4 + p][s0 + v];
                    zi[p][v] = su.d.zt[1][pg * 4 + p][s0 + v];
                }
#pragma unroll
            for (int v = 0; v < 8; ++v) {
                const float4 er = *(const float4*)&su.d.e2[0][s0 + v][jg * 4];
                const float4 ei = *(const float4*)&su.d.e2[1][s0 + v][jg * 4];
#pragma unroll
                for (int p = 0; p < 4; ++p) {
                    acc[p][0] += zr[p][v] * er.x - zi[p][v] * ei.x;
                    acc[p][1] += zr[p][v] * er.y - zi[p][v] * ei.y;
                    acc[p][2] += zr[p][v] * er.z - zi[p][v] * ei.z;
                    acc[p][3] += zr[p][v] * er.w - zi[p][v] * ei.w;
                }
            }
        }
#pragma unroll
        for (int p = 0; p < 4; ++p) {
            float4 r;
            r.x = acc[p][0]; r.y = acc[p][1]; r.z = acc[p][2]; r.w = acc[p][3];
            *(float4*)&out[(size_t)(pc * 64 + pg * 4 + p) * NN + jt * 64 + jg * 4] = r;
        }
    }
}

extern "C" void kernel_launch(void* const* d_in, const int* in_sizes, int n_in,
                              void* d_out, int out_size, void* d_ws, size_t ws_size,
                              hipStream_t stream) {
    const float* x  = (const float*)d_in[0];
    const float* wr = (const float*)d_in[1];
    const float* wi = (const float*)d_in[2];
    float* out = (float*)d_out;
    float* ws  = (float*)d_ws;
    (void)in_sizes; (void)n_in; (void)out_size; (void)ws_size;   // needs ~0.5 MB

    k_cft<<<512, 256, 0, stream>>>(x, ws);
    k_mixicft<<<512, 256, 0, stream>>>(wr, wi, ws, out);
}

// Round 10
// 32.487 us; speedup vs baseline: 1.0878x; 1.0878x over previous
//
#include <hip/hip_runtime.h>

// Spectral conv, 2 dispatches:
//   K1 (k_cft):    X[bc][m] = sum_l T[l][m] * (sum_k xq[bc][l,k] * F[k][m])
//                  + zeroes 512 per-block flags for K2's join.
//   K2 (k_mixicft): phase C: Y = mix(X,W); Z (system-scope stores);
//                   per-producer FLAG (one store, no RMW) -> per-b flag join
//                   (wave-0 lanes poll 64 flags in parallel);
//                   phase D: out = sum_s Re(Z * wf_s e^{2pi i fq_s t_j})
// v10: round-9's counter barrier (64 serialized far-RMWs/line) replaced by
// contention-free flags: producers store to distinct 64B lines, consumers
// poll with system-scope relaxed loads.

#define NN 4096
#define C1_19 0.9863613034027223   // cos(pi/19)
#define NS3 33
#define NSP 40

// ws float offsets
#define OFF_XRE 0                  // X real [512*64]
#define OFF_XIM 32768
#define OFF_Z   65536              // Z [2][512][NSP]
#define OFF_FLG 106496             // 512 uint flags, stride 16 (64B lines)

__device__ __forceinline__ float sin_rev(float r) { return __builtin_amdgcn_sinf(r); }
__device__ __forceinline__ float cos_rev(float r) { return __builtin_amdgcn_cosf(r); }

// nd[k] = cos(pi k/19); cwd[k] = CC weight (endpoints halved). No libm.
// Contains one __syncthreads; caller must sync again before using cwd.
__device__ __forceinline__ void build_tables(double* nd, double* cwd, int t) {
    if (t == 0) {
        nd[0] = 1.0; nd[1] = C1_19;
        for (int k = 2; k < 20; ++k) nd[k] = 2.0 * C1_19 * nd[k - 1] - nd[k - 2];
    }
    __syncthreads();
    if (t < 20) {
        double v = 1.0;
        for (int j = 1; j <= 9; ++j) {
            int q = (2 * j * t) % 38; if (q > 19) q = 38 - q;   // cos(2pi j t/19)
            v -= 2.0 / (4.0 * j * j - 1.0) * nd[q];
        }
        double w = 2.0 * v / 19.0;
        if (t == 0 || t == 19) w *= 0.5;
        cwd[t] = w;
    }
}

// ---------- K1: full CFT, one bc row per block; zero K2 flags ----------
__global__ __launch_bounds__(256) void k_cft(const float* __restrict__ x,
                                             float* __restrict__ ws) {
    __shared__ double nd[20], cwd[20];
    __shared__ __align__(16) float xs[NN];
    __shared__ __align__(16) float xq[2000];
    __shared__ __align__(16) float Fri[20][64][2];
    __shared__ float red[4][64][2];
    const int t = threadIdx.x;
    const int bc = blockIdx.x;
    if (bc == 0) {
#pragma unroll
        for (int it = 0; it < 2; ++it)
            __hip_atomic_store((unsigned*)ws + OFF_FLG + (it * 256 + t) * 16, 0u,
                               __ATOMIC_RELAXED, __HIP_MEMORY_SCOPE_SYSTEM);
    }
    build_tables(nd, cwd, t);
#pragma unroll
    for (int it = 0; it < 4; ++it) {
        int c4 = it * 256 + t;
        *(float4*)&xs[c4 * 4] = *(const float4*)&x[(size_t)bc * NN + c4 * 4];
    }
    __syncthreads();
    // F[k][m] = 0.005*w_k * exp(-2pi i * 0.005*m*node_k)
    for (int idx = t; idx < 1280; idx += 256) {
        int k = idx >> 6, m = idx & 63;
        double r = -0.005 * nd[k] * (double)m;
        r -= floor(r);
        float fr = (float)r;
        float w = (float)(0.005 * cwd[k]);
        Fri[k][m][0] = w * cos_rev(fr);
        Fri[k][m][1] = w * sin_rev(fr);
    }
    // xq: interp x onto the 2000 Chebyshev quadrature nodes
#pragma unroll
    for (int it = 0; it < 8; ++it) {
        int node = it * 256 + t;
        if (node < 2000) {
            int l = node / 20, k = node - l * 20;
            double tq = 0.005 * ((double)(2 * l + 1) + nd[k]);
            double sf = tq * 4095.0;
            int i = (int)sf; if (i > 4094) i = 4094;
            double a = sf - (double)i;
            if (a < 0.0) a = 0.0; if (a > 1.0) a = 1.0;
            float af = (float)a;
            xq[node] = (1.f - af) * xs[i] + af * xs[i + 1];
        }
    }
    __syncthreads();
    const int m = t & 63, grp = t >> 6;
    float Fre[20], Fim[20];
#pragma unroll
    for (int k = 0; k < 20; ++k) {
        Fre[k] = Fri[k][m][0];
        Fim[k] = Fri[k][m][1];
    }
    // main loop: exact integer twiddle phase u/200 (sign folded: sin -> -sin)
    float ar = 0.f, ai = 0.f;
    for (int l = grp * 25; l < grp * 25 + 25; ++l) {
        const float4* q4 = (const float4*)&xq[l * 20];   // wave-uniform addr
        float ur = 0.f, ui = 0.f;
#pragma unroll
        for (int c = 0; c < 5; ++c) {
            float4 q = q4[c];
            ur += q.x * Fre[c * 4]     + q.y * Fre[c * 4 + 1]
                + q.z * Fre[c * 4 + 2] + q.w * Fre[c * 4 + 3];
            ui += q.x * Fim[c * 4]     + q.y * Fim[c * 4 + 1]
                + q.z * Fim[c * 4 + 2] + q.w * Fim[c * 4 + 3];
        }
        int u = (m * (2 * l + 1)) % 200;                 // phase = -u/200 rev
        float fr = (float)u * 0.005f;
        float tr = cos_rev(fr), ti = -sin_rev(fr);
        ar += tr * ur - ti * ui;
        ai += tr * ui + ti * ur;
    }
    red[grp][m][0] = ar;
    red[grp][m][1] = ai;
    __syncthreads();
    if (t < 64) {
        float sr = (red[0][t][0] + red[1][t][0]) + (red[2][t][0] + red[3][t][0]);
        float si = (red[0][t][1] + red[1][t][1]) + (red[2][t][1] + red[3][t][1]);
        ws[OFF_XRE + (size_t)bc * 64 + t] = sr;
        ws[OFF_XIM + (size_t)bc * 64 + t] = si;
    }
}

// ---------- K2: mix+Z, per-b flag join, ICFT. grid 512 = (b<<6 | u) ----------
struct PhC { float part[4][2][64]; float yt[2][64]; };
struct PhD { float zt[2][64][41]; float e2[2][NSP][64]; };
union SU2 { PhC c; PhD d; };

__global__ __launch_bounds__(256) void k_mixicft(const float* __restrict__ wr,
                                                 const float* __restrict__ wi,
                                                 float* __restrict__ ws,
                                                 float* __restrict__ out) {
    __shared__ SU2 su;
    __shared__ double nd[20], cwd[20];
    __shared__ float sw0[NS3], sw1[NS3];
    __shared__ int   si0[NS3], si1[NS3];
    __shared__ double sfq[NS3];
    __shared__ float  swf[NS3];
    const int t = threadIdx.x;
    const int b = blockIdx.x >> 6, u = blockIdx.x & 63;
    build_tables(nd, cwd, t);
    __syncthreads();
    if (t < NS3) {
        int l = (t < 2) ? 49 : (t < 22 ? 50 : 51);
        int k = (t < 2) ? t : (t < 22 ? t - 2 : t - 13);
        double fq = -2048.0 + ((double)l + 0.5) * 40.95 + 20.475 * nd[k];
        sfq[t] = fq;
        swf[t] = (float)(20.475 * cwd[k]);
        int m0 = (int)floor(fq);
        float fr = (float)(fq - (double)m0);
        sw0[t] = (m0 >= 0 && m0 <= 63) ? (1.f - fr) : 0.f;
        sw1[t] = (m0 + 1 >= 0 && m0 + 1 <= 63) ? fr : 0.f;
        si0[t] = min(max(m0, 0), 63);
        si1[t] = min(max(m0 + 1, 0), 63);
    }
    // ---- phase C: Y[b][o=u][m], then Z (system-scope stores) ----
    {
        const int o = u;
        const int m = t & 63, grp = t >> 6;
        float yr = 0.f, yi = 0.f;
#pragma unroll 4
        for (int i = grp * 16; i < grp * 16 + 16; ++i) {
            float xr = ws[OFF_XRE + (size_t)(b * 64 + i) * 64 + m];
            float xi = ws[OFF_XIM + (size_t)(b * 64 + i) * 64 + m];
            float a = wr[((size_t)i * 64 + o) * 64 + m];
            float c = wi[((size_t)i * 64 + o) * 64 + m];
            yr += xr * a - xi * c;
            yi += xr * c + xi * a;
        }
        su.c.part[grp][0][m] = yr;
        su.c.part[grp][1][m] = yi;
        __syncthreads();
        if (t < 128) {
            int pr = t >> 6, mm = t & 63;
            su.c.yt[pr][mm] = ((su.c.part[0][pr][mm] + su.c.part[1][pr][mm]) +
                               (su.c.part[2][pr][mm] + su.c.part[3][pr][mm]));
        }
        __syncthreads();
        if (t < 2 * NS3) {
            int p = t >= NS3, s = t - p * NS3;
            float z = sw0[s] * su.c.yt[p][si0[s]] + sw1[s] * su.c.yt[p][si1[s]];
            __hip_atomic_store(&ws[OFF_Z + (size_t)p * 512 * NSP +
                                   ((size_t)b * 64 + o) * NSP + s],
                               z, __ATOMIC_RELAXED, __HIP_MEMORY_SCOPE_SYSTEM);
        } else if (t < 2 * NS3 + 14) {
            int q = t - 2 * NS3;
            int p = q / 7, s = NS3 + q % 7;
            __hip_atomic_store(&ws[OFF_Z + (size_t)p * 512 * NSP +
                                   ((size_t)b * 64 + o) * NSP + s],
                               0.f, __ATOMIC_RELAXED, __HIP_MEMORY_SCOPE_SYSTEM);
        }
    }
    // ---- join: producer sets own flag (one store); wave 0 polls 64 flags ----
    __syncthreads();                       // drains vmcnt: Z stores complete
    if (t == 0)
        __hip_atomic_store((unsigned*)ws + OFF_FLG + (size_t)blockIdx.x * 16, 1u,
                           __ATOMIC_RELAXED, __HIP_MEMORY_SCOPE_SYSTEM);
    if (t < 64) {
        unsigned* fp = (unsigned*)ws + OFF_FLG + (size_t)(b * 64 + t) * 16;
        while (__hip_atomic_load(fp, __ATOMIC_RELAXED, __HIP_MEMORY_SCOPE_SYSTEM) == 0u)
            __builtin_amdgcn_s_sleep(2);
    }
    __syncthreads();
    // ---- phase D: ICFT for (pc=b, jt=u) ----
    {
        const int jt = u, pc = b;
        for (int idx = t; idx < 2 * 64 * NSP; idx += 256) {
            int part = idx / (64 * NSP), rem = idx % (64 * NSP);
            int row = rem / NSP, s = rem % NSP;
            su.d.zt[part][row][s] =
                ws[OFF_Z + (size_t)part * 512 * NSP + ((size_t)pc * 64 + row) * NSP + s];
        }
        __syncthreads();
        const double inv4095 = 1.0 / 4095.0;
        for (int idx = t; idx < NSP * 64; idx += 256) {
            int s = idx >> 6, jl = idx & 63;
            float cr = 0.f, ci = 0.f;
            if (s < NS3) {
                double ph = sfq[s] * ((double)(jt * 64 + jl) * inv4095);
                ph -= floor(ph);
                float fr = (float)ph;
                cr = swf[s] * cos_rev(fr);
                ci = swf[s] * sin_rev(fr);
            }
            su.d.e2[0][s][jl] = cr;
            su.d.e2[1][s][jl] = ci;
        }
        __syncthreads();
        const int jg = t & 15, pg = t >> 4;
        float acc[4][4] = {{0.f}};
        for (int s0 = 0; s0 < NSP; s0 += 8) {
            float zr[4][8], zi[4][8];
#pragma unroll
            for (int p = 0; p < 4; ++p)
#pragma unroll
                for (int v = 0; v < 8; ++v) {
                    zr[p][v] = su.d.zt[0][pg * 4 + p][s0 + v];
                    zi[p][v] = su.d.zt[1][pg * 4 + p][s0 + v];
                }
#pragma unroll
            for (int v = 0; v < 8; ++v) {
                const float4 er = *(const float4*)&su.d.e2[0][s0 + v][jg * 4];
                const float4 ei = *(const float4*)&su.d.e2[1][s0 + v][jg * 4];
#pragma unroll
                for (int p = 0; p < 4; ++p) {
                    acc[p][0] += zr[p][v] * er.x - zi[p][v] * ei.x;
                    acc[p][1] += zr[p][v] * er.y - zi[p][v] * ei.y;
                    acc[p][2] += zr[p][v] * er.z - zi[p][v] * ei.z;
                    acc[p][3] += zr[p][v] * er.w - zi[p][v] * ei.w;
                }
            }
        }
#pragma unroll
        for (int p = 0; p < 4; ++p) {
            float4 r;
            r.x = acc[p][0]; r.y = acc[p][1]; r.z = acc[p][2]; r.w = acc[p][3];
            *(float4*)&out[(size_t)(pc * 64 + pg * 4 + p) * NN + jt * 64 + jg * 4] = r;
        }
    }
}

extern "C" void kernel_launch(void* const* d_in, const int* in_sizes, int n_in,
                              void* d_out, int out_size, void* d_ws, size_t ws_size,
                              hipStream_t stream) {
    const float* x  = (const float*)d_in[0];
    const float* wr = (const float*)d_in[1];
    const float* wi = (const float*)d_in[2];
    float* out = (float*)d_out;
    float* ws  = (float*)d_ws;
    (void)in_sizes; (void)n_in; (void)out_size; (void)ws_size;   // needs ~0.5 MB

    k_cft<<<512, 256, 0, stream>>>(x, ws);
    k_mixicft<<<512, 256, 0, stream>>>(wr, wi, ws, out);
}

// Round 11
// 31.174 us; speedup vs baseline: 1.1336x; 1.0421x over previous
//
#include <hip/hip_runtime.h>

// Spectral conv, 3 dispatches, occupancy-doubled:
//   K1 (k_cft):  X-half[h][bc][m] = sum_{l in half h} T[l][m]*(sum_k xq*F[k][m])
//                grid (512 bc, 2 h) = 1024 blocks, 16 waves/CU.
//   K2 (k_mix):  Y = mix(X0+X1, W); Z[p][bo][s] (plain stores). 512 blocks.
//   K3 (k_icft): out = sum_s Re(Z * wf_s e^{2pi i fq_s t_j}); grid (128 jt2, 8 pc)
//                = 1024 blocks (32-j tiles), 16 waves/CU.

#define NN 4096
#define C1_19 0.9863613034027223   // cos(pi/19)
#define NS3 33
#define NSP 40

// ws float offsets: X planes per half h: base = h*65536
#define OFF_XRE 0                  // X real [512*64]
#define OFF_XIM 32768
#define OFF_Z   131072             // Z [2][512][NSP]

__device__ __forceinline__ float sin_rev(float r) { return __builtin_amdgcn_sinf(r); }
__device__ __forceinline__ float cos_rev(float r) { return __builtin_amdgcn_cosf(r); }

// nd[k] = cos(pi k/19); cwd[k] = CC weight (endpoints halved). No libm.
// Contains one __syncthreads; caller must sync again before using cwd.
__device__ __forceinline__ void build_tables(double* nd, double* cwd, int t) {
    if (t == 0) {
        nd[0] = 1.0; nd[1] = C1_19;
        for (int k = 2; k < 20; ++k) nd[k] = 2.0 * C1_19 * nd[k - 1] - nd[k - 2];
    }
    __syncthreads();
    if (t < 20) {
        double v = 1.0;
        for (int j = 1; j <= 9; ++j) {
            int q = (2 * j * t) % 38; if (q > 19) q = 38 - q;   // cos(2pi j t/19)
            v -= 2.0 / (4.0 * j * j - 1.0) * nd[q];
        }
        double w = 2.0 * v / 19.0;
        if (t == 0 || t == 19) w *= 0.5;
        cwd[t] = w;
    }
}

// ---------- K1: CFT half-partials; grid (512 bc, 2 h) ----------
__global__ __launch_bounds__(256) void k_cft(const float* __restrict__ x,
                                             float* __restrict__ ws) {
    __shared__ double nd[20], cwd[20];
    __shared__ __align__(16) float xs[2052];        // half-row window
    __shared__ __align__(16) float xq[1000];        // 50 segments x 20 nodes
    __shared__ __align__(16) float Fri[20][64][2];
    __shared__ float red[4][64][2];
    const int t = threadIdx.x;
    const int bc = blockIdx.x, h = blockIdx.y;
    const int i0 = h ? 2044 : 0;
    build_tables(nd, cwd, t);
    // stage window (513 float4)
    for (int idx = t; idx < 513; idx += 256)
        *(float4*)&xs[idx * 4] = *(const float4*)&x[(size_t)bc * NN + i0 + idx * 4];
    __syncthreads();
    // F[k][m] = 0.005*w_k * exp(-2pi i * 0.005*m*node_k)
    for (int idx = t; idx < 1280; idx += 256) {
        int k = idx >> 6, m = idx & 63;
        double r = -0.005 * nd[k] * (double)m;
        r -= floor(r);
        float fr = (float)r;
        float w = (float)(0.005 * cwd[k]);
        Fri[k][m][0] = w * cos_rev(fr);
        Fri[k][m][1] = w * sin_rev(fr);
    }
    // interp onto this half's 1000 cheb nodes
    for (int idx = t; idx < 1000; idx += 256) {
        int l_loc = idx / 20, k = idx - l_loc * 20;
        int l = h * 50 + l_loc;
        double tq = 0.005 * ((double)(2 * l + 1) + nd[k]);
        double sf = tq * 4095.0;
        int i = (int)sf; if (i > 4094) i = 4094;
        double a = sf - (double)i;
        if (a < 0.0) a = 0.0; if (a > 1.0) a = 1.0;
        float af = (float)a;
        xq[idx] = (1.f - af) * xs[i - i0] + af * xs[i - i0 + 1];
    }
    __syncthreads();
    const int m = t & 63, grp = t >> 6;
    float Fre[20], Fim[20];
#pragma unroll
    for (int k = 0; k < 20; ++k) {
        Fre[k] = Fri[k][m][0];
        Fim[k] = Fri[k][m][1];
    }
    // strided segment loop; exact integer twiddle (sin sign folded)
    float ar = 0.f, ai = 0.f;
    for (int l_loc = grp; l_loc < 50; l_loc += 4) {
        const float4* q4 = (const float4*)&xq[l_loc * 20];   // wave-uniform
        float ur = 0.f, ui = 0.f;
#pragma unroll
        for (int c = 0; c < 5; ++c) {
            float4 q = q4[c];
            ur += q.x * Fre[c * 4]     + q.y * Fre[c * 4 + 1]
                + q.z * Fre[c * 4 + 2] + q.w * Fre[c * 4 + 3];
            ui += q.x * Fim[c * 4]     + q.y * Fim[c * 4 + 1]
                + q.z * Fim[c * 4 + 2] + q.w * Fim[c * 4 + 3];
        }
        int l = h * 50 + l_loc;
        int u = (m * (2 * l + 1)) % 200;                 // phase = -u/200 rev
        float fr = (float)u * 0.005f;
        float tr = cos_rev(fr), ti = -sin_rev(fr);
        ar += tr * ur - ti * ui;
        ai += tr * ui + ti * ur;
    }
    red[grp][m][0] = ar;
    red[grp][m][1] = ai;
    __syncthreads();
    if (t < 64) {
        float sr = (red[0][t][0] + red[1][t][0]) + (red[2][t][0] + red[3][t][0]);
        float si = (red[0][t][1] + red[1][t][1]) + (red[2][t][1] + red[3][t][1]);
        const int base = h * 65536;
        ws[base + OFF_XRE + (size_t)bc * 64 + t] = sr;
        ws[base + OFF_XIM + (size_t)bc * 64 + t] = si;
    }
}

// ---------- K2: mix (sums X halves) + Z; grid 512 = (b, o) ----------
__global__ __launch_bounds__(256) void k_mix(const float* __restrict__ wr,
                                             const float* __restrict__ wi,
                                             float* __restrict__ ws) {
    __shared__ double nd[20], cwd[20];
    __shared__ float part[4][2][64];
    __shared__ float yt[2][64];
    __shared__ float sw0[NS3], sw1[NS3];
    __shared__ int   si0[NS3], si1[NS3];
    const int t = threadIdx.x;
    const int b = blockIdx.x >> 6, o = blockIdx.x & 63;
    build_tables(nd, cwd, t);
    __syncthreads();
    if (t < NS3) {
        int l = (t < 2) ? 49 : (t < 22 ? 50 : 51);
        int k = (t < 2) ? t : (t < 22 ? t - 2 : t - 13);
        double fq = -2048.0 + ((double)l + 0.5) * 40.95 + 20.475 * nd[k];
        int m0 = (int)floor(fq);
        float fr = (float)(fq - (double)m0);
        sw0[t] = (m0 >= 0 && m0 <= 63) ? (1.f - fr) : 0.f;
        sw1[t] = (m0 + 1 >= 0 && m0 + 1 <= 63) ? fr : 0.f;
        si0[t] = min(max(m0, 0), 63);
        si1[t] = min(max(m0 + 1, 0), 63);
    }
    const int m = t & 63, grp = t >> 6;
    float yr = 0.f, yi = 0.f;
#pragma unroll 4
    for (int i = grp * 16; i < grp * 16 + 16; ++i) {
        const size_t off = (size_t)(b * 64 + i) * 64 + m;
        float xr = ws[OFF_XRE + off] + ws[65536 + OFF_XRE + off];
        float xi = ws[OFF_XIM + off] + ws[65536 + OFF_XIM + off];
        float a = wr[((size_t)i * 64 + o) * 64 + m];
        float c = wi[((size_t)i * 64 + o) * 64 + m];
        yr += xr * a - xi * c;
        yi += xr * c + xi * a;
    }
    part[grp][0][m] = yr;
    part[grp][1][m] = yi;
    __syncthreads();
    if (t < 128) {
        int pr = t >> 6, mm = t & 63;
        yt[pr][mm] = ((part[0][pr][mm] + part[1][pr][mm]) +
                      (part[2][pr][mm] + part[3][pr][mm]));
    }
    __syncthreads();
    if (t < 2 * NS3) {
        int p = t >= NS3, s = t - p * NS3;
        float z = sw0[s] * yt[p][si0[s]] + sw1[s] * yt[p][si1[s]];
        ws[OFF_Z + (size_t)p * 512 * NSP + ((size_t)b * 64 + o) * NSP + s] = z;
    } else if (t < 2 * NS3 + 14) {
        int q = t - 2 * NS3;
        int p = q / 7, s = NS3 + q % 7;
        ws[OFF_Z + (size_t)p * 512 * NSP + ((size_t)b * 64 + o) * NSP + s] = 0.f;
    }
}

// ---------- K3: ICFT; grid (128 jt2, 8 pc), 32-j tiles ----------
__global__ __launch_bounds__(256) void k_icft(const float* __restrict__ ws,
                                              float* __restrict__ out) {
    __shared__ double nd[20], cwd[20];
    __shared__ double sfq[NS3];
    __shared__ float  swf[NS3];
    __shared__ __align__(16) float zt[2][64][41];
    __shared__ __align__(16) float e2[2][NSP][36];
    const int t = threadIdx.x;
    const int jt2 = blockIdx.x, pc = blockIdx.y;
    build_tables(nd, cwd, t);
    __syncthreads();
    if (t < NS3) {
        int l = (t < 2) ? 49 : (t < 22 ? 50 : 51);
        int k = (t < 2) ? t : (t < 22 ? t - 2 : t - 13);
        sfq[t] = -2048.0 + ((double)l + 0.5) * 40.95 + 20.475 * nd[k];
        swf[t] = (float)(20.475 * cwd[k]);
    }
    for (int idx = t; idx < 2 * 64 * NSP; idx += 256) {
        int part = idx / (64 * NSP), rem = idx % (64 * NSP);
        int row = rem / NSP, s = rem % NSP;
        zt[part][row][s] =
            ws[OFF_Z + (size_t)part * 512 * NSP + ((size_t)pc * 64 + row) * NSP + s];
    }
    __syncthreads();
    const double inv4095 = 1.0 / 4095.0;
    for (int idx = t; idx < NSP * 32; idx += 256) {
        int s = idx >> 5, jl = idx & 31;
        float cr = 0.f, ci = 0.f;
        if (s < NS3) {
            double ph = sfq[s] * ((double)(jt2 * 32 + jl) * inv4095);
            ph -= floor(ph);
            float fr = (float)ph;
            cr = swf[s] * cos_rev(fr);
            ci = swf[s] * sin_rev(fr);
        }
        e2[0][s][jl + (jl >> 3) * 0] = cr;   // linear [s][jl]
        e2[1][s][jl] = ci;
        e2[0][s][jl] = cr;
    }
    __syncthreads();
    const int jg = t & 7, pg = t >> 3;      // 8 j-groups x 32 pair-groups
    float acc[2][4] = {{0.f}};
    for (int s0 = 0; s0 < NSP; s0 += 8) {
        float zr[2][8], zi[2][8];
#pragma unroll
        for (int p = 0; p < 2; ++p)
#pragma unroll
            for (int v = 0; v < 8; ++v) {
                zr[p][v] = zt[0][pg * 2 + p][s0 + v];
                zi[p][v] = zt[1][pg * 2 + p][s0 + v];
            }
#pragma unroll
        for (int v = 0; v < 8; ++v) {
            const float4 er = *(const float4*)&e2[0][s0 + v][jg * 4];
            const float4 ei = *(const float4*)&e2[1][s0 + v][jg * 4];
#pragma unroll
            for (int p = 0; p < 2; ++p) {
                acc[p][0] += zr[p][v] * er.x - zi[p][v] * ei.x;
                acc[p][1] += zr[p][v] * er.y - zi[p][v] * ei.y;
                acc[p][2] += zr[p][v] * er.z - zi[p][v] * ei.z;
                acc[p][3] += zr[p][v] * er.w - zi[p][v] * ei.w;
            }
        }
    }
#pragma unroll
    for (int p = 0; p < 2; ++p) {
        float4 r;
        r.x = acc[p][0]; r.y = acc[p][1]; r.z = acc[p][2]; r.w = acc[p][3];
        *(float4*)&out[(size_t)(pc * 64 + pg * 2 + p) * NN + jt2 * 32 + jg * 4] = r;
    }
}

extern "C" void kernel_launch(void* const* d_in, const int* in_sizes, int n_in,
                              void* d_out, int out_size, void* d_ws, size_t ws_size,
                              hipStream_t stream) {
    const float* x  = (const float*)d_in[0];
    const float* wr = (const float*)d_in[1];
    const float* wi = (const float*)d_in[2];
    float* out = (float*)d_out;
    float* ws  = (float*)d_ws;
    (void)in_sizes; (void)n_in; (void)out_size; (void)ws_size;   // needs ~0.7 MB

    k_cft<<<dim3(512, 2), 256, 0, stream>>>(x, ws);
    k_mix<<<512, 256, 0, stream>>>(wr, wi, ws);
    k_icft<<<dim3(128, 8), 256, 0, stream>>>(ws, out);
}

// Round 12
// 29.890 us; speedup vs baseline: 1.1823x; 1.0430x over previous
//
#include <hip/hip_runtime.h>

// Spectral conv, 2 dispatches with producer/consumer overlap:
//   D1 (k_cftmix), 1024 blocks:
//     blocks 0-511:  CFT  X[bc][m] = sum_l T[l][m]*(sum_k xq*F[k][m])
//                    X via system-scope stores; flag MAGIC into out[bc*16].
//     blocks 512+:   mix block (b,o): prefetch W-slice to LDS (overlaps CFT),
//                    poll 64 flags, Y = mix(X,W), Z[p][(b,o)][s] plain stores.
//   D2 (k_icft):     out = sum_s Re(Z * wf_s e^{2pi i fq_s t_j})
// Flags in d_out: NaN-payload MAGIC; D2 overwrites all of out each launch,
// so no reset dispatch is needed and replays stay deterministic.

#define NN 4096
#define C1_19 0.9863613034027223   // cos(pi/19)
#define NS3 33
#define NSP 40
#define MAGIC 0x7fc0deadu

// ws float offsets
#define OFF_XRE 0                  // X real [512*64]
#define OFF_XIM 32768
#define OFF_Z   65536              // Z [2][512][NSP]

__device__ __forceinline__ float sin_rev(float r) { return __builtin_amdgcn_sinf(r); }
__device__ __forceinline__ float cos_rev(float r) { return __builtin_amdgcn_cosf(r); }

// nd[k] = cos(pi k/19); cwd[k] = CC weight (endpoints halved). No libm.
// Contains one __syncthreads; caller must sync again before using cwd.
__device__ __forceinline__ void build_tables(double* nd, double* cwd, int t) {
    if (t == 0) {
        nd[0] = 1.0; nd[1] = C1_19;
        for (int k = 2; k < 20; ++k) nd[k] = 2.0 * C1_19 * nd[k - 1] - nd[k - 2];
    }
    __syncthreads();
    if (t < 20) {
        double v = 1.0;
        for (int j = 1; j <= 9; ++j) {
            int q = (2 * j * t) % 38; if (q > 19) q = 38 - q;   // cos(2pi j t/19)
            v -= 2.0 / (4.0 * j * j - 1.0) * nd[q];
        }
        double w = 2.0 * v / 19.0;
        if (t == 0 || t == 19) w *= 0.5;
        cwd[t] = w;
    }
}

struct PA { float xs[NN]; float xq[2000]; float Fri[20][64][2]; float red[4][64][2]; };
struct PB { float wsl[2][64][64]; float part[4][2][64]; float yt[2][64]; };
union SU { PA a; PB b; };

// ---------- D1: CFT producers + mix consumers, one dispatch ----------
__global__ __launch_bounds__(256, 4) void k_cftmix(const float* __restrict__ x,
                                                   const float* __restrict__ wr,
                                                   const float* __restrict__ wi,
                                                   float* __restrict__ ws,
                                                   float* __restrict__ out) {
    __shared__ SU su;
    __shared__ double nd[20], cwd[20];
    __shared__ float sw0[NS3], sw1[NS3];
    __shared__ int   si0[NS3], si1[NS3];
    const int t = threadIdx.x;
    const int vb = blockIdx.x;

    if (vb < 512) {
        // ================= CFT producer: row bc = vb =================
        const int bc = vb;
        build_tables(nd, cwd, t);
#pragma unroll
        for (int it = 0; it < 4; ++it) {
            int c4 = it * 256 + t;
            *(float4*)&su.a.xs[c4 * 4] = *(const float4*)&x[(size_t)bc * NN + c4 * 4];
        }
        __syncthreads();
        // F[k][m] = 0.005*w_k * exp(-2pi i * 0.005*m*node_k)
        for (int idx = t; idx < 1280; idx += 256) {
            int k = idx >> 6, m = idx & 63;
            double r = -0.005 * nd[k] * (double)m;
            r -= floor(r);
            float fr = (float)r;
            float w = (float)(0.005 * cwd[k]);
            su.a.Fri[k][m][0] = w * cos_rev(fr);
            su.a.Fri[k][m][1] = w * sin_rev(fr);
        }
        // xq: interp onto the 2000 cheb nodes
#pragma unroll
        for (int it = 0; it < 8; ++it) {
            int node = it * 256 + t;
            if (node < 2000) {
                int l = node / 20, k = node - l * 20;
                double tq = 0.005 * ((double)(2 * l + 1) + nd[k]);
                double sf = tq * 4095.0;
                int i = (int)sf; if (i > 4094) i = 4094;
                double a = sf - (double)i;
                if (a < 0.0) a = 0.0; if (a > 1.0) a = 1.0;
                float af = (float)a;
                su.a.xq[node] = (1.f - af) * su.a.xs[i] + af * su.a.xs[i + 1];
            }
        }
        __syncthreads();
        const int m = t & 63, grp = t >> 6;
        float Fre[20], Fim[20];
#pragma unroll
        for (int k = 0; k < 20; ++k) {
            Fre[k] = su.a.Fri[k][m][0];
            Fim[k] = su.a.Fri[k][m][1];
        }
        float ar = 0.f, ai = 0.f;
        for (int l = grp * 25; l < grp * 25 + 25; ++l) {
            const float4* q4 = (const float4*)&su.a.xq[l * 20];   // wave-uniform
            float ur = 0.f, ui = 0.f;
#pragma unroll
            for (int c = 0; c < 5; ++c) {
                float4 q = q4[c];
                ur += q.x * Fre[c * 4]     + q.y * Fre[c * 4 + 1]
                    + q.z * Fre[c * 4 + 2] + q.w * Fre[c * 4 + 3];
                ui += q.x * Fim[c * 4]     + q.y * Fim[c * 4 + 1]
                    + q.z * Fim[c * 4 + 2] + q.w * Fim[c * 4 + 3];
            }
            int u = (m * (2 * l + 1)) % 200;                 // phase = -u/200 rev
            float fr = (float)u * 0.005f;
            float tr = cos_rev(fr), ti = -sin_rev(fr);
            ar += tr * ur - ti * ui;
            ai += tr * ui + ti * ur;
        }
        su.a.red[grp][m][0] = ar;
        su.a.red[grp][m][1] = ai;
        __syncthreads();
        if (t < 64) {
            float sr = (su.a.red[0][t][0] + su.a.red[1][t][0]) +
                       (su.a.red[2][t][0] + su.a.red[3][t][0]);
            float si = (su.a.red[0][t][1] + su.a.red[1][t][1]) +
                       (su.a.red[2][t][1] + su.a.red[3][t][1]);
            __hip_atomic_store(&ws[OFF_XRE + (size_t)bc * 64 + t], sr,
                               __ATOMIC_RELAXED, __HIP_MEMORY_SCOPE_SYSTEM);
            __hip_atomic_store(&ws[OFF_XIM + (size_t)bc * 64 + t], si,
                               __ATOMIC_RELAXED, __HIP_MEMORY_SCOPE_SYSTEM);
        }
        __syncthreads();                 // drains vmcnt: X stores complete
        if (t == 0)
            __hip_atomic_store((unsigned*)out + (size_t)bc * 16, MAGIC,
                               __ATOMIC_RELAXED, __HIP_MEMORY_SCOPE_SYSTEM);
    } else {
        // ================= mix consumer: (b, o) =================
        const int id = vb - 512;
        const int b = id >> 6, o = id & 63;
        build_tables(nd, cwd, t);
        __syncthreads();
        if (t < NS3) {
            int l = (t < 2) ? 49 : (t < 22 ? 50 : 51);
            int k = (t < 2) ? t : (t < 22 ? t - 2 : t - 13);
            double fq = -2048.0 + ((double)l + 0.5) * 40.95 + 20.475 * nd[k];
            int m0 = (int)floor(fq);
            float fr = (float)(fq - (double)m0);
            sw0[t] = (m0 >= 0 && m0 <= 63) ? (1.f - fr) : 0.f;
            sw1[t] = (m0 + 1 >= 0 && m0 + 1 <= 63) ? fr : 0.f;
            si0[t] = min(max(m0, 0), 63);
            si1[t] = min(max(m0 + 1, 0), 63);
        }
        // W prefetch into LDS — overlaps the CFT blocks' compute phase
        for (int idx = t; idx < 2048; idx += 256) {
            int arr = idx >> 10, rem = idx & 1023;
            int i = rem >> 4, c4 = rem & 15;
            const float* src = arr ? wi : wr;
            *(float4*)&su.b.wsl[arr][i][c4 * 4] =
                *(const float4*)&src[(((size_t)i * 64 + o) << 6) + c4 * 4];
        }
        // join: wait for all 64 CFT rows of this b
        if (t < 64) {
            const unsigned* fp = (const unsigned*)out + (size_t)(b * 64 + t) * 16;
            while (__hip_atomic_load(fp, __ATOMIC_RELAXED,
                                     __HIP_MEMORY_SCOPE_SYSTEM) != MAGIC)
                __builtin_amdgcn_s_sleep(2);
        }
        __syncthreads();
        // mix: Y[b][o][m]; X plain loads (fresh lines, producers wrote through)
        const int m = t & 63, grp = t >> 6;
        float yr = 0.f, yi = 0.f;
#pragma unroll 4
        for (int i = grp * 16; i < grp * 16 + 16; ++i) {
            const size_t off = (size_t)(b * 64 + i) * 64 + m;
            float xr = ws[OFF_XRE + off];
            float xi = ws[OFF_XIM + off];
            float a = su.b.wsl[0][i][m];
            float c = su.b.wsl[1][i][m];
            yr += xr * a - xi * c;
            yi += xr * c + xi * a;
        }
        su.b.part[grp][0][m] = yr;
        su.b.part[grp][1][m] = yi;
        __syncthreads();
        if (t < 128) {
            int pr = t >> 6, mm = t & 63;
            su.b.yt[pr][mm] = ((su.b.part[0][pr][mm] + su.b.part[1][pr][mm]) +
                               (su.b.part[2][pr][mm] + su.b.part[3][pr][mm]));
        }
        __syncthreads();
        if (t < 2 * NS3) {
            int p = t >= NS3, s = t - p * NS3;
            float z = sw0[s] * su.b.yt[p][si0[s]] + sw1[s] * su.b.yt[p][si1[s]];
            ws[OFF_Z + (size_t)p * 512 * NSP + ((size_t)b * 64 + o) * NSP + s] = z;
        } else if (t < 2 * NS3 + 14) {
            int q = t - 2 * NS3;
            int p = q / 7, s = NS3 + q % 7;
            ws[OFF_Z + (size_t)p * 512 * NSP + ((size_t)b * 64 + o) * NSP + s] = 0.f;
        }
    }
}

// ---------- D2: ICFT; grid (128 jt2, 8 pc), 32-j tiles ----------
__global__ __launch_bounds__(256) void k_icft(const float* __restrict__ ws,
                                              float* __restrict__ out) {
    __shared__ double nd[20], cwd[20];
    __shared__ double sfq[NS3];
    __shared__ float  swf[NS3];
    __shared__ __align__(16) float zt[2][64][41];
    __shared__ __align__(16) float e2[2][NSP][36];
    const int t = threadIdx.x;
    const int jt2 = blockIdx.x, pc = blockIdx.y;
    build_tables(nd, cwd, t);
    __syncthreads();
    if (t < NS3) {
        int l = (t < 2) ? 49 : (t < 22 ? 50 : 51);
        int k = (t < 2) ? t : (t < 22 ? t - 2 : t - 13);
        sfq[t] = -2048.0 + ((double)l + 0.5) * 40.95 + 20.475 * nd[k];
        swf[t] = (float)(20.475 * cwd[k]);
    }
    for (int idx = t; idx < 2 * 64 * NSP; idx += 256) {
        int part = idx / (64 * NSP), rem = idx % (64 * NSP);
        int row = rem / NSP, s = rem % NSP;
        zt[part][row][s] =
            ws[OFF_Z + (size_t)part * 512 * NSP + ((size_t)pc * 64 + row) * NSP + s];
    }
    __syncthreads();
    const double inv4095 = 1.0 / 4095.0;
    for (int idx = t; idx < NSP * 32; idx += 256) {
        int s = idx >> 5, jl = idx & 31;
        float cr = 0.f, ci = 0.f;
        if (s < NS3) {
            double ph = sfq[s] * ((double)(jt2 * 32 + jl) * inv4095);
            ph -= floor(ph);
            float fr = (float)ph;
            cr = swf[s] * cos_rev(fr);
            ci = swf[s] * sin_rev(fr);
        }
        e2[0][s][jl] = cr;
        e2[1][s][jl] = ci;
    }
    __syncthreads();
    const int jg = t & 7, pg = t >> 3;      // 8 j-groups x 32 pair-groups
    float acc[2][4] = {{0.f}};
    for (int s0 = 0; s0 < NSP; s0 += 8) {
        float zr[2][8], zi[2][8];
#pragma unroll
        for (int p = 0; p < 2; ++p)
#pragma unroll
            for (int v = 0; v < 8; ++v) {
                zr[p][v] = zt[0][pg * 2 + p][s0 + v];
                zi[p][v] = zt[1][pg * 2 + p][s0 + v];
            }
#pragma unroll
        for (int v = 0; v < 8; ++v) {
            const float4 er = *(const float4*)&e2[0][s0 + v][jg * 4];
            const float4 ei = *(const float4*)&e2[1][s0 + v][jg * 4];
#pragma unroll
            for (int p = 0; p < 2; ++p) {
                acc[p][0] += zr[p][v] * er.x - zi[p][v] * ei.x;
                acc[p][1] += zr[p][v] * er.y - zi[p][v] * ei.y;
                acc[p][2] += zr[p][v] * er.z - zi[p][v] * ei.z;
                acc[p][3] += zr[p][v] * er.w - zi[p][v] * ei.w;
            }
        }
    }
#pragma unroll
    for (int p = 0; p < 2; ++p) {
        float4 r;
        r.x = acc[p][0]; r.y = acc[p][1]; r.z = acc[p][2]; r.w = acc[p][3];
        *(float4*)&out[(size_t)(pc * 64 + pg * 2 + p) * NN + jt2 * 32 + jg * 4] = r;
    }
}

extern "C" void kernel_launch(void* const* d_in, const int* in_sizes, int n_in,
                              void* d_out, int out_size, void* d_ws, size_t ws_size,
                              hipStream_t stream) {
    const float* x  = (const float*)d_in[0];
    const float* wr = (const float*)d_in[1];
    const float* wi = (const float*)d_in[2];
    float* out = (float*)d_out;
    float* ws  = (float*)d_ws;
    (void)in_sizes; (void)n_in; (void)out_size; (void)ws_size;   // needs ~0.5 MB

    k_cftmix<<<1024, 256, 0, stream>>>(x, wr, wi, ws, out);
    k_icft<<<dim3(128, 8), 256, 0, stream>>>(ws, out);
}